// Round 1
// baseline (335.627 us; speedup 1.0000x reference)
//
#include <hip/hip_runtime.h>
#include <stdint.h>

#define AS1 __attribute__((address_space(1)))
#define AS3 __attribute__((address_space(3)))

typedef __attribute__((ext_vector_type(8))) __bf16 bf16x8;
typedef __attribute__((ext_vector_type(4))) float f32x4;
typedef __attribute__((ext_vector_type(4))) unsigned int u32x4;
typedef __attribute__((ext_vector_type(2))) unsigned int u32x2;

static __device__ __forceinline__ void gload16(const void* g, void* l) {
    // async global->LDS, 16B per lane; LDS dest must be linear (base + lane*16)
    __builtin_amdgcn_global_load_lds((AS1 void*)(uintptr_t)g, (AS3 void*)l, 16, 0, 0);
}

static __device__ __forceinline__ unsigned cvt_pk_bf16(float lo, float hi) {
    unsigned r;
    asm volatile("v_cvt_pk_bf16_f32 %0, %1, %2" : "=v"(r) : "v"(lo), "v"(hi));
    return r;
}
static __device__ __forceinline__ unsigned short f2bf(float f) {
    return (unsigned short)(cvt_pk_bf16(f, 0.f) & 0xffffu);
}

static __device__ __forceinline__ f32x4 mfma16(bf16x8 a, bf16x8 b, f32x4 c) {
    return __builtin_amdgcn_mfma_f32_16x16x32_bf16(a, b, c, 0, 0, 0);
}

// ---------------------------------------------------------------------------
// Weight transpose + convert: W[k][n] f32 (1024x1024) -> Wt[n][k] bf16
// ---------------------------------------------------------------------------
__global__ __launch_bounds__(256) void k_wtrans(const float* __restrict__ W,
                                                unsigned short* __restrict__ Wt) {
    __shared__ unsigned short tile[64][72];   // [n][k], padded
    const int tid = threadIdx.x;
    const int k0 = blockIdx.x * 64, n0 = blockIdx.y * 64;
#pragma unroll
    for (int j = 0; j < 4; ++j) {
        int c = j * 256 + tid;                // 1024 float4 chunks
        int kr = c >> 4, c4 = c & 15;
        f32x4 v = *(const f32x4*)(W + (size_t)(k0 + kr) * 1024 + n0 + c4 * 4);
#pragma unroll
        for (int e = 0; e < 4; ++e) tile[c4 * 4 + e][kr] = f2bf(v[e]);
    }
    __syncthreads();
#pragma unroll
    for (int j = 0; j < 2; ++j) {
        int c = j * 256 + tid;                // 512 chunks of 8 bf16
        int nr = c >> 3, kc = c & 7;
        union { unsigned short s[8]; u32x4 v; } t;
#pragma unroll
        for (int e = 0; e < 8; ++e) t.s[e] = tile[nr][kc * 8 + e];
        *(u32x4*)(Wt + (size_t)(n0 + nr) * 1024 + k0 + kc * 8) = t.v;
    }
}

// ---------------------------------------------------------------------------
// GEMM: C[M][N] = A[M][K] * Bt[N][K]^T + bias[N]
//   A_F32:  A is f32 (staged f32 in LDS, converted at ds_read); else bf16
//   OUT_F32: C f32; else bf16
// Tile 64x128, BK=64, 4 waves (2 along M x 2 along N), each 32x64.
// ---------------------------------------------------------------------------
template <int A_F32, int OUT_F32>
__global__ __launch_bounds__(256) void k_gemm(const void* __restrict__ Ap,
                                              const unsigned short* __restrict__ Bt,
                                              const float* __restrict__ bias,
                                              void* __restrict__ Cp,
                                              int M, int N, int K) {
    __shared__ __align__(16) char smem[32 * 1024];
    char* sA = smem;              // f32: [64][16 chunks] swizzled; bf16: [64][8 chunks]
    char* sB = smem + 16 * 1024;  // [128][8 chunks of 16B] swizzled
    const int tid = threadIdx.x;
    const int wave = tid >> 6, lane = tid & 63, g = lane >> 4, l16 = lane & 15;
    const int wm = wave & 1, wn = wave >> 1;
    const int m0 = blockIdx.x * 64, n0 = blockIdx.y * 128;

    f32x4 acc[2][4];
#pragma unroll
    for (int i = 0; i < 2; ++i)
#pragma unroll
        for (int j = 0; j < 4; ++j) acc[i][j] = (f32x4){0.f, 0.f, 0.f, 0.f};

    const int nkt = K >> 6;
    for (int kt = 0; kt < nkt; ++kt) {
        const int k0 = kt << 6;
        __syncthreads();
        if constexpr (A_F32) {
            const float* A = (const float*)Ap;
#pragma unroll
            for (int j = 0; j < 4; ++j) {
                int c = j * 256 + tid;
                int row = c >> 4, w = c & 15, kc = w ^ (row & 15);
                gload16(A + (size_t)(m0 + row) * K + k0 + kc * 4, sA + c * 16);
            }
        } else {
            const unsigned short* A = (const unsigned short*)Ap;
#pragma unroll
            for (int j = 0; j < 2; ++j) {
                int c = j * 256 + tid;
                int row = c >> 3, w = c & 7, kc = w ^ (row & 7);
                gload16(A + (size_t)(m0 + row) * K + k0 + kc * 8, sA + c * 16);
            }
        }
#pragma unroll
        for (int j = 0; j < 4; ++j) {
            int c = j * 256 + tid;
            int row = c >> 3, w = c & 7, kc = w ^ (row & 7);
            gload16(Bt + (size_t)(n0 + row) * K + k0 + kc * 8, sB + c * 16);
        }
        __syncthreads();
#pragma unroll
        for (int ks = 0; ks < 2; ++ks) {
            bf16x8 af[2];
#pragma unroll
            for (int mi = 0; mi < 2; ++mi) {
                int row = wm * 32 + mi * 16 + l16;
                if constexpr (A_F32) {
                    int c0 = (ks * 8 + g * 2) ^ (row & 15);
                    int c1 = (ks * 8 + g * 2 + 1) ^ (row & 15);
                    f32x4 lo = *(const f32x4*)(sA + row * 256 + c0 * 16);
                    f32x4 hi = *(const f32x4*)(sA + row * 256 + c1 * 16);
                    union { unsigned u[4]; bf16x8 v; } cv;
                    cv.u[0] = cvt_pk_bf16(lo[0], lo[1]);
                    cv.u[1] = cvt_pk_bf16(lo[2], lo[3]);
                    cv.u[2] = cvt_pk_bf16(hi[0], hi[1]);
                    cv.u[3] = cvt_pk_bf16(hi[2], hi[3]);
                    af[mi] = cv.v;
                } else {
                    int c = (ks * 4 + g) ^ (row & 7);
                    af[mi] = *(const bf16x8*)(sA + row * 128 + c * 16);
                }
            }
#pragma unroll
            for (int ni = 0; ni < 4; ++ni) {
                int row = wn * 64 + ni * 16 + l16;
                int c = (ks * 4 + g) ^ (row & 7);
                bf16x8 bfr = *(const bf16x8*)(sB + row * 128 + c * 16);
#pragma unroll
                for (int mi = 0; mi < 2; ++mi)
                    acc[mi][ni] = mfma16(af[mi], bfr, acc[mi][ni]);
            }
        }
    }
    // epilogue: bias + store. C/D layout: col = lane&15, row = g*4 + r
#pragma unroll
    for (int ni = 0; ni < 4; ++ni) {
        int col = n0 + wn * 64 + ni * 16 + l16;
        float bn = bias[col];
#pragma unroll
        for (int mi = 0; mi < 2; ++mi) {
            int rbase = m0 + wm * 32 + mi * 16 + g * 4;
#pragma unroll
            for (int r = 0; r < 4; ++r) {
                float v = acc[mi][ni][r] + bn;
                if constexpr (OUT_F32)
                    ((float*)Cp)[(size_t)(rbase + r) * N + col] = v;
                else
                    ((unsigned short*)Cp)[(size_t)(rbase + r) * N + col] = f2bf(v);
            }
        }
    }
}

// ---------------------------------------------------------------------------
// Per-head V transpose: V2[(b*2048+s)][1024] bf16 -> Vt[(bh*64+d)][2048] bf16
// ---------------------------------------------------------------------------
__global__ __launch_bounds__(256) void k_vtrans(const unsigned short* __restrict__ V2,
                                                unsigned short* __restrict__ Vt) {
    __shared__ unsigned short tile[64][72];   // [d][s]
    const int tid = threadIdx.x;
    const int s0 = blockIdx.x * 64;
    const int bh = blockIdx.y, b = bh >> 4, h = bh & 15;
#pragma unroll
    for (int j = 0; j < 2; ++j) {
        int c = j * 256 + tid;
        int sr = c >> 3, dc = c & 7;
        union { u32x4 v; unsigned short s[8]; } t;
        t.v = *(const u32x4*)(V2 + (size_t)(b * 2048 + s0 + sr) * 1024 + h * 64 + dc * 8);
#pragma unroll
        for (int e = 0; e < 8; ++e) tile[dc * 8 + e][sr] = t.s[e];
    }
    __syncthreads();
#pragma unroll
    for (int j = 0; j < 2; ++j) {
        int c = j * 256 + tid;
        int dr = c >> 3, sc = c & 7;
        union { unsigned short s[8]; u32x4 v; } t;
#pragma unroll
        for (int e = 0; e < 8; ++e) t.s[e] = tile[dr][sc * 8 + e];
        *(u32x4*)(Vt + ((size_t)bh * 64 + dr) * 2048 + s0 + sc * 8) = t.v;
    }
}

// ---------------------------------------------------------------------------
// Causal flash attention.
// Grid (S/64, B*H). 4 waves/block, wave w owns q rows [qb+16w, qb+16w+16).
// Swapped QK^T: S^T tile via mfma(K, Q) -> lane owns q = lane&15 (softmax
// lane-local). P -> per-wave swizzled LDS -> PV as O^T = V^T * P^T.
// ---------------------------------------------------------------------------
__global__ __launch_bounds__(256) void k_attn(const unsigned short* __restrict__ Q2,
                                              const unsigned short* __restrict__ K2,
                                              const unsigned short* __restrict__ Vt,
                                              float* __restrict__ ctx) {
    __shared__ __align__(16) char plds[4][2048];   // per-wave P^T buffer 16q x 64kv bf16
    const int tid = threadIdx.x, w = tid >> 6, lane = tid & 63;
    const int g = lane >> 4, l16 = lane & 15;
    const int qb = blockIdx.x * 64;
    const int bh = blockIdx.y, b = bh >> 4, h = bh & 15;
    const int qrow = qb + w * 16;
    const int qg = qrow + l16;                 // q owned by this lane (column)
    const int swz = (l16 & 7) << 4;

    const unsigned short* qp = Q2 + (size_t)(b * 2048 + qrow + l16) * 1024 + h * 64;
    bf16x8 qf0 = *(const bf16x8*)(qp + g * 8);
    bf16x8 qf1 = *(const bf16x8*)(qp + 32 + g * 8);

    f32x4 accO[4];
#pragma unroll
    for (int i = 0; i < 4; ++i) accO[i] = (f32x4){0.f, 0.f, 0.f, 0.f};
    float m = -1e30f, lsum = 0.f;
    char* myp = plds[w];
    const unsigned short* kbase = K2 + (size_t)(b * 2048) * 1024 + h * 64 + g * 8;
    const unsigned short* vbase = Vt + ((size_t)bh * 64 + l16) * 2048 + g * 8;

    for (int kv0 = 0; kv0 < qrow + 16; kv0 += 64) {
        float s[16];
#pragma unroll
        for (int blk = 0; blk < 4; ++blk) {
            const unsigned short* kp = kbase + (size_t)(kv0 + blk * 16 + l16) * 1024;
            bf16x8 kf0 = *(const bf16x8*)kp;
            bf16x8 kf1 = *(const bf16x8*)(kp + 32);
            f32x4 a = (f32x4){0.f, 0.f, 0.f, 0.f};
            a = mfma16(kf0, qf0, a);
            a = mfma16(kf1, qf1, a);
#pragma unroll
            for (int r = 0; r < 4; ++r) {
                int kvg = kv0 + blk * 16 + g * 4 + r;
                float v = a[r] * 0.125f;
                s[blk * 4 + r] = (kvg <= qg) ? v : -1e9f;
            }
        }
        float mx = s[0];
#pragma unroll
        for (int j = 1; j < 16; ++j) mx = fmaxf(mx, s[j]);
        mx = fmaxf(mx, __shfl_xor(mx, 16));
        mx = fmaxf(mx, __shfl_xor(mx, 32));
        float mnew = fmaxf(m, mx);
        float scale = __expf(m - mnew);
        m = mnew;
        float ps = 0.f;
        unsigned pk[8];
#pragma unroll
        for (int j = 0; j < 8; ++j) {
            float p0 = __expf(s[2 * j] - mnew);
            float p1 = __expf(s[2 * j + 1] - mnew);
            ps += p0 + p1;
            pk[j] = cvt_pk_bf16(p0, p1);
        }
        ps += __shfl_xor(ps, 16);
        ps += __shfl_xor(ps, 32);
        lsum = lsum * scale + ps;
#pragma unroll
        for (int dt = 0; dt < 4; ++dt) accO[dt] = accO[dt] * scale;
        // write P^T (bf16) to swizzled LDS: logical byte q*128 + kv*2
#pragma unroll
        for (int blk = 0; blk < 4; ++blk) {
            u32x2 pw = {pk[blk * 2], pk[blk * 2 + 1]};
            *(u32x2*)(myp + l16 * 128 + ((blk * 32 + g * 8) ^ swz)) = pw;
        }
        // PV: O^T[d][q] += V^T * P^T
#pragma unroll
        for (int kvh = 0; kvh < 2; ++kvh) {
            bf16x8 pf = *(const bf16x8*)(myp + l16 * 128 + ((kvh * 64 + g * 16) ^ swz));
#pragma unroll
            for (int dt = 0; dt < 4; ++dt) {
                bf16x8 vf = *(const bf16x8*)(vbase + (size_t)dt * 16 * 2048 + kv0 + kvh * 32);
                accO[dt] = mfma16(vf, pf, accO[dt]);
            }
        }
    }
    float inv = 1.f / lsum;
    // O^T: lane owns col q=l16; row d = dt*16 + g*4 + r  -> ctx f32 [4096][1024]
    float* cp = ctx + (size_t)(b * 2048 + qb + w * 16 + l16) * 1024 + h * 64 + g * 4;
#pragma unroll
    for (int dt = 0; dt < 4; ++dt) {
        f32x4 o;
#pragma unroll
        for (int r = 0; r < 4; ++r) o[r] = accO[dt][r] * inv;
        *(f32x4*)(cp + dt * 16) = o;
    }
}

// ---------------------------------------------------------------------------
extern "C" void kernel_launch(void* const* d_in, const int* in_sizes, int n_in,
                              void* d_out, int out_size, void* d_ws, size_t ws_size,
                              hipStream_t stream) {
    const float* query = (const float*)d_in[0];
    const float* key   = (const float*)d_in[1];
    const float* value = (const float*)d_in[2];
    // d_in[3] = mask: fixed causal tril, applied analytically
    const float* wq = (const float*)d_in[4];
    const float* bq = (const float*)d_in[5];
    const float* wk = (const float*)d_in[6];
    const float* bk = (const float*)d_in[7];
    const float* wv = (const float*)d_in[8];
    const float* bv = (const float*)d_in[9];
    const float* wo = (const float*)d_in[10];
    const float* bo = (const float*)d_in[11];
    float* out = (float*)d_out;

    char* ws = (char*)d_ws;
    unsigned short* Wtq = (unsigned short*)ws;                 // 4 x 2MB
    unsigned short* Wtk = Wtq + 1024 * 1024;
    unsigned short* Wtv = Wtk + 1024 * 1024;
    unsigned short* Wto = Wtv + 1024 * 1024;
    unsigned short* Q2  = Wto + 1024 * 1024;                   // 3 x 8MB bf16 [4096][1024]
    unsigned short* K2  = Q2 + 4096 * 1024;
    unsigned short* V2  = K2 + 4096 * 1024;
    unsigned short* Vt  = V2 + 4096 * 1024;                    // 8MB bf16 [32*64][2048]
    float* ctx = (float*)(Vt + 4096 * 1024);                   // 16MB f32 [4096][1024]

    dim3 blk(256);
    k_wtrans<<<dim3(16, 16), blk, 0, stream>>>(wq, Wtq);
    k_wtrans<<<dim3(16, 16), blk, 0, stream>>>(wk, Wtk);
    k_wtrans<<<dim3(16, 16), blk, 0, stream>>>(wv, Wtv);
    k_wtrans<<<dim3(16, 16), blk, 0, stream>>>(wo, Wto);

    k_gemm<1, 0><<<dim3(64, 8), blk, 0, stream>>>(query, Wtq, bq, Q2, 4096, 1024, 1024);
    k_gemm<1, 0><<<dim3(64, 8), blk, 0, stream>>>(key,   Wtk, bk, K2, 4096, 1024, 1024);
    k_gemm<1, 0><<<dim3(64, 8), blk, 0, stream>>>(value, Wtv, bv, V2, 4096, 1024, 1024);

    k_vtrans<<<dim3(32, 32), blk, 0, stream>>>(V2, Vt);
    k_attn<<<dim3(32, 32), blk, 0, stream>>>(Q2, K2, Vt, ctx);

    k_gemm<1, 1><<<dim3(64, 8), blk, 0, stream>>>(ctx, Wto, bo, out, 4096, 1024, 1024);
}

// Round 2
// 163.504 us; speedup vs baseline: 2.0527x; 2.0527x over previous
//
#include <hip/hip_runtime.h>
#include <stdint.h>

#define AS1 __attribute__((address_space(1)))
#define AS3 __attribute__((address_space(3)))

typedef __attribute__((ext_vector_type(8))) __bf16 bf16x8;
typedef __attribute__((ext_vector_type(4))) float f32x4;
typedef __attribute__((ext_vector_type(4))) unsigned int u32x4;
typedef __attribute__((ext_vector_type(2))) unsigned int u32x2;

static __device__ __forceinline__ void gload16(const void* g, void* l) {
    // async global->LDS, 16B per lane; LDS dest must be linear (base + lane*16)
    __builtin_amdgcn_global_load_lds((AS1 void*)(uintptr_t)g, (AS3 void*)l, 16, 0, 0);
}

static __device__ __forceinline__ unsigned cvt_pk_bf16(float lo, float hi) {
    unsigned r;
    asm volatile("v_cvt_pk_bf16_f32 %0, %1, %2" : "=v"(r) : "v"(lo), "v"(hi));
    return r;
}
static __device__ __forceinline__ unsigned short f2bf(float f) {
    return (unsigned short)(cvt_pk_bf16(f, 0.f) & 0xffffu);
}

static __device__ __forceinline__ f32x4 mfma16(bf16x8 a, bf16x8 b, f32x4 c) {
    return __builtin_amdgcn_mfma_f32_16x16x32_bf16(a, b, c, 0, 0, 0);
}

// ---------------------------------------------------------------------------
// Weight transpose + convert: W[k][n] f32 (1024x1024) -> Wt[n][k] bf16
// ---------------------------------------------------------------------------
__global__ __launch_bounds__(256) void k_wtrans(const float* __restrict__ W,
                                                unsigned short* __restrict__ Wt) {
    __shared__ unsigned short tile[64][72];   // [n][k], padded
    const int tid = threadIdx.x;
    const int k0 = blockIdx.x * 64, n0 = blockIdx.y * 64;
#pragma unroll
    for (int j = 0; j < 4; ++j) {
        int c = j * 256 + tid;                // 1024 float4 chunks
        int kr = c >> 4, c4 = c & 15;
        f32x4 v = *(const f32x4*)(W + (size_t)(k0 + kr) * 1024 + n0 + c4 * 4);
#pragma unroll
        for (int e = 0; e < 4; ++e) tile[c4 * 4 + e][kr] = f2bf(v[e]);
    }
    __syncthreads();
#pragma unroll
    for (int j = 0; j < 2; ++j) {
        int c = j * 256 + tid;                // 512 chunks of 8 bf16
        int nr = c >> 3, kc = c & 7;
        union { unsigned short s[8]; u32x4 v; } t;
#pragma unroll
        for (int e = 0; e < 8; ++e) t.s[e] = tile[nr][kc * 8 + e];
        *(u32x4*)(Wt + (size_t)(n0 + nr) * 1024 + k0 + kc * 8) = t.v;
    }
}

// ---------------------------------------------------------------------------
// GEMM: C[M][N] = (A[M][K] * Bt[N][K]^T + bias[N]) * cscale
//   A_F32:  A is f32 (staged f32 in LDS, converted at ds_read); else bf16
//   OUT_F32: C f32; else bf16
// Tile 64x128, BK=64, 4 waves (2 along M x 2 along N), each 32x64.
// ---------------------------------------------------------------------------
template <int A_F32, int OUT_F32>
__global__ __launch_bounds__(256) void k_gemm(const void* __restrict__ Ap,
                                              const unsigned short* __restrict__ Bt,
                                              const float* __restrict__ bias,
                                              void* __restrict__ Cp,
                                              int M, int N, int K, float cscale) {
    __shared__ __align__(16) char smem[32 * 1024];
    char* sA = smem;              // f32: [64][16 chunks] swizzled; bf16: [64][8 chunks]
    char* sB = smem + 16 * 1024;  // [128][8 chunks of 16B] swizzled
    const int tid = threadIdx.x;
    const int wave = tid >> 6, lane = tid & 63, g = lane >> 4, l16 = lane & 15;
    const int wm = wave & 1, wn = wave >> 1;
    const int m0 = blockIdx.x * 64, n0 = blockIdx.y * 128;

    f32x4 acc[2][4];
#pragma unroll
    for (int i = 0; i < 2; ++i)
#pragma unroll
        for (int j = 0; j < 4; ++j) acc[i][j] = (f32x4){0.f, 0.f, 0.f, 0.f};

    const int nkt = K >> 6;
    for (int kt = 0; kt < nkt; ++kt) {
        const int k0 = kt << 6;
        __syncthreads();
        if constexpr (A_F32) {
            const float* A = (const float*)Ap;
#pragma unroll
            for (int j = 0; j < 4; ++j) {
                int c = j * 256 + tid;
                int row = c >> 4, w = c & 15, kc = w ^ (row & 15);
                gload16(A + (size_t)(m0 + row) * K + k0 + kc * 4, sA + c * 16);
            }
        } else {
            const unsigned short* A = (const unsigned short*)Ap;
#pragma unroll
            for (int j = 0; j < 2; ++j) {
                int c = j * 256 + tid;
                int row = c >> 3, w = c & 7, kc = w ^ (row & 7);
                gload16(A + (size_t)(m0 + row) * K + k0 + kc * 8, sA + c * 16);
            }
        }
#pragma unroll
        for (int j = 0; j < 4; ++j) {
            int c = j * 256 + tid;
            int row = c >> 3, w = c & 7, kc = w ^ (row & 7);
            gload16(Bt + (size_t)(n0 + row) * K + k0 + kc * 8, sB + c * 16);
        }
        __syncthreads();
#pragma unroll
        for (int ks = 0; ks < 2; ++ks) {
            bf16x8 af[2];
#pragma unroll
            for (int mi = 0; mi < 2; ++mi) {
                int row = wm * 32 + mi * 16 + l16;
                if constexpr (A_F32) {
                    int c0 = (ks * 8 + g * 2) ^ (row & 15);
                    int c1 = (ks * 8 + g * 2 + 1) ^ (row & 15);
                    f32x4 lo = *(const f32x4*)(sA + row * 256 + c0 * 16);
                    f32x4 hi = *(const f32x4*)(sA + row * 256 + c1 * 16);
                    union { unsigned u[4]; bf16x8 v; } cv;
                    cv.u[0] = cvt_pk_bf16(lo[0], lo[1]);
                    cv.u[1] = cvt_pk_bf16(lo[2], lo[3]);
                    cv.u[2] = cvt_pk_bf16(hi[0], hi[1]);
                    cv.u[3] = cvt_pk_bf16(hi[2], hi[3]);
                    af[mi] = cv.v;
                } else {
                    int c = (ks * 4 + g) ^ (row & 7);
                    af[mi] = *(const bf16x8*)(sA + row * 128 + c * 16);
                }
            }
#pragma unroll
            for (int ni = 0; ni < 4; ++ni) {
                int row = wn * 64 + ni * 16 + l16;
                int c = (ks * 4 + g) ^ (row & 7);
                bf16x8 bfr = *(const bf16x8*)(sB + row * 128 + c * 16);
#pragma unroll
                for (int mi = 0; mi < 2; ++mi)
                    acc[mi][ni] = mfma16(af[mi], bfr, acc[mi][ni]);
            }
        }
    }
    // epilogue: bias + scale + store. C/D layout: col = lane&15, row = g*4 + r
#pragma unroll
    for (int ni = 0; ni < 4; ++ni) {
        int col = n0 + wn * 64 + ni * 16 + l16;
        float bn = bias[col];
#pragma unroll
        for (int mi = 0; mi < 2; ++mi) {
            int rbase = m0 + wm * 32 + mi * 16 + g * 4;
#pragma unroll
            for (int r = 0; r < 4; ++r) {
                float v = (acc[mi][ni][r] + bn) * cscale;
                if constexpr (OUT_F32)
                    ((float*)Cp)[(size_t)(rbase + r) * N + col] = v;
                else
                    ((unsigned short*)Cp)[(size_t)(rbase + r) * N + col] = f2bf(v);
            }
        }
    }
}

// ---------------------------------------------------------------------------
// Per-head V transpose: V2[(b*2048+s)][1024] bf16 -> Vt[(bh*64+d)][2048] bf16
// ---------------------------------------------------------------------------
__global__ __launch_bounds__(256) void k_vtrans(const unsigned short* __restrict__ V2,
                                                unsigned short* __restrict__ Vt) {
    __shared__ unsigned short tile[64][72];   // [d][s]
    const int tid = threadIdx.x;
    const int s0 = blockIdx.x * 64;
    const int bh = blockIdx.y, b = bh >> 4, h = bh & 15;
#pragma unroll
    for (int j = 0; j < 2; ++j) {
        int c = j * 256 + tid;
        int sr = c >> 3, dc = c & 7;
        union { u32x4 v; unsigned short s[8]; } t;
        t.v = *(const u32x4*)(V2 + (size_t)(b * 2048 + s0 + sr) * 1024 + h * 64 + dc * 8);
#pragma unroll
        for (int e = 0; e < 8; ++e) tile[dc * 8 + e][sr] = t.s[e];
    }
    __syncthreads();
#pragma unroll
    for (int j = 0; j < 2; ++j) {
        int c = j * 256 + tid;
        int dr = c >> 3, sc = c & 7;
        union { unsigned short s[8]; u32x4 v; } t;
#pragma unroll
        for (int e = 0; e < 8; ++e) t.s[e] = tile[dr][sc * 8 + e];
        *(u32x4*)(Vt + ((size_t)bh * 64 + dr) * 2048 + s0 + sc * 8) = t.v;
    }
}

// ---------------------------------------------------------------------------
// Causal flash attention, staged + load-balanced.
// Grid (8, B*H). 8 waves (512 thr). Block x handles q-tiles {x, 15-x} of 128
// rows each -> every block does exactly 34 kv-tiles of 64 (uniform work).
// K-tile [64][64] and V^T-tile [64][64] staged in XOR-swizzled LDS via
// global_load_lds (linear dest + pre-swizzled source), double-buffered,
// stage-before-compute. Swapped QK^T (lane owns q = lane&15 -> softmax
// lane-local). P -> per-wave swizzled LDS -> PV as O^T = V^T * P^T.
// Scale 1/sqrt(64) is pre-folded into Q2 by the Q-projection GEMM.
// ---------------------------------------------------------------------------
__global__ __launch_bounds__(512) void k_attn(const unsigned short* __restrict__ Q2,
                                              const unsigned short* __restrict__ K2,
                                              const unsigned short* __restrict__ Vt,
                                              float* __restrict__ ctx) {
    __shared__ __align__(16) char sK[2][8192];   // 64 kv x 64 d bf16, chunk-swizzled
    __shared__ __align__(16) char sV[2][8192];   // 64 d x 64 kv bf16, chunk-swizzled
    __shared__ __align__(16) char sP[8][2048];   // per-wave P^T: 16 q x 64 kv bf16

    const int tid = threadIdx.x, w = tid >> 6, lane = tid & 63;
    const int g = lane >> 4, l16 = lane & 15;
    const int bh = blockIdx.y, b = bh >> 4, h = bh & 15;
    const int swzl = (l16 & 7) << 4;

    // staging source addresses (rule 21: pre-swizzled source, linear LDS dest)
    const int srow = tid >> 3;                    // 0..63
    const int ssc = (tid & 7) ^ (srow & 7);       // swizzled source chunk
    const unsigned short* ksrc = K2 + (size_t)(b * 2048 + srow) * 1024 + h * 64 + ssc * 8;
    const unsigned short* vsrc = Vt + ((size_t)bh * 64 + srow) * 2048 + ssc * 8;

    char* const myp = sP[w];

#pragma unroll 1
    for (int t2 = 0; t2 < 2; ++t2) {
        const int tile = t2 ? (15 - blockIdx.x) : blockIdx.x;
        const int tb = tile * 128;
        const int wq0 = tb + w * 16;              // first q row of this wave
        const int qg = wq0 + l16;                 // q owned by this lane

        const unsigned short* qp = Q2 + (size_t)(b * 2048 + wq0 + l16) * 1024 + h * 64;
        bf16x8 qf0 = *(const bf16x8*)(qp + g * 8);
        bf16x8 qf1 = *(const bf16x8*)(qp + 32 + g * 8);

        f32x4 accO[4];
#pragma unroll
        for (int i = 0; i < 4; ++i) accO[i] = (f32x4){0.f, 0.f, 0.f, 0.f};
        float m = -1e30f, lsum = 0.f;

        const int nkv = 2 * tile + 2;
        __syncthreads();                           // prev tile's reads done
        gload16(ksrc, sK[0] + tid * 16);
        gload16(vsrc, sV[0] + tid * 16);

#pragma unroll 1
        for (int kt = 0; kt < nkv; ++kt) {
            const int cur = kt & 1;
            const int kv0 = kt * 64;
            __syncthreads();                       // drains vmcnt: buf[cur] ready
            if (kt + 1 < nkv) {
                gload16(ksrc + (size_t)(kv0 + 64) * 1024, sK[cur ^ 1] + tid * 16);
                gload16(vsrc + (kv0 + 64), sV[cur ^ 1] + tid * 16);
            }
            if (kv0 < wq0 + 16) {                  // wave has unmasked scores
                const char* kb = sK[cur];
                const char* vb = sV[cur];
                const bool needmask = (kv0 + 63 > wq0);
                float s[16];
#pragma unroll
                for (int blk = 0; blk < 4; ++blk) {
                    const int rl = blk * 16 + l16;
                    const char* krow = kb + rl * 128;
                    bf16x8 kf0 = *(const bf16x8*)(krow + ((g << 4) ^ swzl));
                    bf16x8 kf1 = *(const bf16x8*)(krow + (((4 + g) << 4) ^ swzl));
                    f32x4 a = (f32x4){0.f, 0.f, 0.f, 0.f};
                    a = mfma16(kf0, qf0, a);
                    a = mfma16(kf1, qf1, a);
                    if (needmask) {
#pragma unroll
                        for (int r = 0; r < 4; ++r) {
                            int kvg = kv0 + blk * 16 + g * 4 + r;
                            s[blk * 4 + r] = (kvg <= qg) ? a[r] : -1e9f;
                        }
                    } else {
#pragma unroll
                        for (int r = 0; r < 4; ++r) s[blk * 4 + r] = a[r];
                    }
                }
                float mx = fmaxf(fmaxf(fmaxf(s[0], s[1]), fmaxf(s[2], s[3])),
                                 fmaxf(fmaxf(s[4], s[5]), fmaxf(s[6], s[7])));
                mx = fmaxf(mx, fmaxf(fmaxf(fmaxf(s[8], s[9]), fmaxf(s[10], s[11])),
                                     fmaxf(fmaxf(s[12], s[13]), fmaxf(s[14], s[15]))));
                mx = fmaxf(mx, __shfl_xor(mx, 16));
                mx = fmaxf(mx, __shfl_xor(mx, 32));
                float mnew = fmaxf(m, mx);
                float scale = __expf(m - mnew);
                m = mnew;
                float ps = 0.f;
                unsigned pk[8];
#pragma unroll
                for (int j = 0; j < 8; ++j) {
                    float p0 = __expf(s[2 * j] - mnew);
                    float p1 = __expf(s[2 * j + 1] - mnew);
                    ps += p0 + p1;
                    pk[j] = cvt_pk_bf16(p0, p1);
                }
                ps += __shfl_xor(ps, 16);
                ps += __shfl_xor(ps, 32);
                lsum = lsum * scale + ps;
#pragma unroll
                for (int dt = 0; dt < 4; ++dt) accO[dt] = accO[dt] * scale;
                // write P^T (bf16) to per-wave swizzled LDS
#pragma unroll
                for (int blk = 0; blk < 4; ++blk) {
                    u32x2 pw = {pk[blk * 2], pk[blk * 2 + 1]};
                    *(u32x2*)(myp + l16 * 128 + ((blk * 32 + g * 8) ^ swzl)) = pw;
                }
                // PV: O^T[d][q] += V^T * P^T
#pragma unroll
                for (int kvh = 0; kvh < 2; ++kvh) {
                    bf16x8 pf = *(const bf16x8*)(myp + l16 * 128 + ((kvh * 64 + g * 16) ^ swzl));
#pragma unroll
                    for (int dt = 0; dt < 4; ++dt) {
                        const int rv = dt * 16 + l16;
                        bf16x8 vf = *(const bf16x8*)(vb + rv * 128 + (((kvh * 4 + g) << 4) ^ swzl));
                        accO[dt] = mfma16(vf, pf, accO[dt]);
                    }
                }
            }
        }
        float inv = 1.f / lsum;
        // O^T: lane owns col q=l16; row d = dt*16 + g*4 + r -> ctx f32 [4096][1024]
        float* cp = ctx + (size_t)(b * 2048 + wq0 + l16) * 1024 + h * 64 + g * 4;
#pragma unroll
        for (int dt = 0; dt < 4; ++dt) {
            f32x4 o;
#pragma unroll
            for (int r = 0; r < 4; ++r) o[r] = accO[dt][r] * inv;
            *(f32x4*)(cp + dt * 16) = o;
        }
    }
}

// ---------------------------------------------------------------------------
extern "C" void kernel_launch(void* const* d_in, const int* in_sizes, int n_in,
                              void* d_out, int out_size, void* d_ws, size_t ws_size,
                              hipStream_t stream) {
    const float* query = (const float*)d_in[0];
    const float* key   = (const float*)d_in[1];
    const float* value = (const float*)d_in[2];
    // d_in[3] = mask: fixed causal tril, applied analytically
    const float* wq = (const float*)d_in[4];
    const float* bq = (const float*)d_in[5];
    const float* wk = (const float*)d_in[6];
    const float* bk = (const float*)d_in[7];
    const float* wv = (const float*)d_in[8];
    const float* bv = (const float*)d_in[9];
    const float* wo = (const float*)d_in[10];
    const float* bo = (const float*)d_in[11];
    float* out = (float*)d_out;

    char* ws = (char*)d_ws;
    unsigned short* Wtq = (unsigned short*)ws;                 // 4 x 2MB
    unsigned short* Wtk = Wtq + 1024 * 1024;
    unsigned short* Wtv = Wtk + 1024 * 1024;
    unsigned short* Wto = Wtv + 1024 * 1024;
    unsigned short* Q2  = Wto + 1024 * 1024;                   // 3 x 8MB bf16 [4096][1024]
    unsigned short* K2  = Q2 + 4096 * 1024;
    unsigned short* V2  = K2 + 4096 * 1024;
    unsigned short* Vt  = V2 + 4096 * 1024;                    // 8MB bf16 [32*64][2048]
    float* ctx = (float*)(Vt + 4096 * 1024);                   // 16MB f32 [4096][1024]

    dim3 blk(256);
    k_wtrans<<<dim3(16, 16), blk, 0, stream>>>(wq, Wtq);
    k_wtrans<<<dim3(16, 16), blk, 0, stream>>>(wk, Wtk);
    k_wtrans<<<dim3(16, 16), blk, 0, stream>>>(wv, Wtv);
    k_wtrans<<<dim3(16, 16), blk, 0, stream>>>(wo, Wto);

    // scale 1/sqrt(d_k)=0.125 folded into Q projection
    k_gemm<1, 0><<<dim3(64, 8), blk, 0, stream>>>(query, Wtq, bq, Q2, 4096, 1024, 1024, 0.125f);
    k_gemm<1, 0><<<dim3(64, 8), blk, 0, stream>>>(key,   Wtk, bk, K2, 4096, 1024, 1024, 1.0f);
    k_gemm<1, 0><<<dim3(64, 8), blk, 0, stream>>>(value, Wtv, bv, V2, 4096, 1024, 1024, 1.0f);

    k_vtrans<<<dim3(32, 32), blk, 0, stream>>>(V2, Vt);
    k_attn<<<dim3(8, 32), dim3(512), 0, stream>>>(Q2, K2, Vt, ctx);

    k_gemm<1, 1><<<dim3(64, 8), blk, 0, stream>>>(ctx, Wto, bo, out, 4096, 1024, 1024, 1.0f);
}

// Round 3
// 143.260 us; speedup vs baseline: 2.3428x; 1.1413x over previous
//
#include <hip/hip_runtime.h>
#include <stdint.h>

#define AS1 __attribute__((address_space(1)))
#define AS3 __attribute__((address_space(3)))

typedef __attribute__((ext_vector_type(8))) __bf16 bf16x8;
typedef __attribute__((ext_vector_type(4))) float f32x4;
typedef __attribute__((ext_vector_type(4))) unsigned int u32x4;
typedef __attribute__((ext_vector_type(2))) unsigned int u32x2;

static __device__ __forceinline__ void gload16(const void* g, void* l) {
    // async global->LDS, 16B per lane; LDS dest must be linear (base + lane*16)
    __builtin_amdgcn_global_load_lds((AS1 void*)(uintptr_t)g, (AS3 void*)l, 16, 0, 0);
}

static __device__ __forceinline__ unsigned cvt_pk_bf16(float lo, float hi) {
    unsigned r;
    asm volatile("v_cvt_pk_bf16_f32 %0, %1, %2" : "=v"(r) : "v"(lo), "v"(hi));
    return r;
}
static __device__ __forceinline__ unsigned short f2bf(float f) {
    return (unsigned short)(cvt_pk_bf16(f, 0.f) & 0xffffu);
}

static __device__ __forceinline__ f32x4 mfma16(bf16x8 a, bf16x8 b, f32x4 c) {
    return __builtin_amdgcn_mfma_f32_16x16x32_bf16(a, b, c, 0, 0, 0);
}

// ---------------------------------------------------------------------------
// Weight transpose + convert: W[k][n] f32 (1024x1024) -> Wt[n][k] bf16
// ---------------------------------------------------------------------------
__global__ __launch_bounds__(256) void k_wtrans(const float* __restrict__ W,
                                                unsigned short* __restrict__ Wt) {
    __shared__ unsigned short tile[64][72];   // [n][k], padded
    const int tid = threadIdx.x;
    const int k0 = blockIdx.x * 64, n0 = blockIdx.y * 64;
#pragma unroll
    for (int j = 0; j < 4; ++j) {
        int c = j * 256 + tid;                // 1024 float4 chunks
        int kr = c >> 4, c4 = c & 15;
        f32x4 v = *(const f32x4*)(W + (size_t)(k0 + kr) * 1024 + n0 + c4 * 4);
#pragma unroll
        for (int e = 0; e < 4; ++e) tile[c4 * 4 + e][kr] = f2bf(v[e]);
    }
    __syncthreads();
#pragma unroll
    for (int j = 0; j < 2; ++j) {
        int c = j * 256 + tid;                // 512 chunks of 8 bf16
        int nr = c >> 3, kc = c & 7;
        union { unsigned short s[8]; u32x4 v; } t;
#pragma unroll
        for (int e = 0; e < 8; ++e) t.s[e] = tile[nr][kc * 8 + e];
        *(u32x4*)(Wt + (size_t)(n0 + nr) * 1024 + k0 + kc * 8) = t.v;
    }
}

// ---------------------------------------------------------------------------
// GEMM: C[M][N] = (A[M][K] * Bt[N][K]^T + bias[N]) * cscale
//   A_F32:  A is f32 (staged f32 in LDS, converted at ds_read); else bf16
//   OUT_F32: C f32; else bf16
// Tile 64x128, BK=64, 4 waves (2 along M x 2 along N), each 32x64.
// Double-buffered LDS, single barrier per K-step: stage(next) issued BEFORE
// compute(cur), barrier at iteration end drains both (T3-minimum pattern).
// ---------------------------------------------------------------------------
template <int A_F32, int OUT_F32>
__global__ __launch_bounds__(256) void k_gemm(const void* __restrict__ Ap,
                                              const unsigned short* __restrict__ Bt,
                                              const float* __restrict__ bias,
                                              void* __restrict__ Cp,
                                              int M, int N, int K, float cscale) {
    extern __shared__ __align__(16) char smem[];
    constexpr int ASZ = A_F32 ? 16384 : 8192;
    char* sA = smem;                 // dbuf: [2][ASZ]
    char* sB = smem + 2 * ASZ;       // dbuf: [2][16384]
    const int tid = threadIdx.x;
    const int wave = tid >> 6, lane = tid & 63, g = lane >> 4, l16 = lane & 15;
    const int wm = wave & 1, wn = wave >> 1;
    const int m0 = blockIdx.x * 64, n0 = blockIdx.y * 128;

    f32x4 acc[2][4];
#pragma unroll
    for (int i = 0; i < 2; ++i)
#pragma unroll
        for (int j = 0; j < 4; ++j) acc[i][j] = (f32x4){0.f, 0.f, 0.f, 0.f};

    auto STAGE = [&](int k0, int buf) {
        if constexpr (A_F32) {
            const float* A = (const float*)Ap;
            char* dst = sA + buf * ASZ;
#pragma unroll
            for (int j = 0; j < 4; ++j) {
                int c = j * 256 + tid;
                int row = c >> 4, w = c & 15, kc = w ^ (row & 15);
                gload16(A + (size_t)(m0 + row) * K + k0 + kc * 4, dst + c * 16);
            }
        } else {
            const unsigned short* A = (const unsigned short*)Ap;
            char* dst = sA + buf * ASZ;
#pragma unroll
            for (int j = 0; j < 2; ++j) {
                int c = j * 256 + tid;
                int row = c >> 3, w = c & 7, kc = w ^ (row & 7);
                gload16(A + (size_t)(m0 + row) * K + k0 + kc * 8, dst + c * 16);
            }
        }
        char* dst = sB + buf * 16384;
#pragma unroll
        for (int j = 0; j < 4; ++j) {
            int c = j * 256 + tid;
            int row = c >> 3, w = c & 7, kc = w ^ (row & 7);
            gload16(Bt + (size_t)(n0 + row) * K + k0 + kc * 8, dst + c * 16);
        }
    };

    const int nkt = K >> 6;
    STAGE(0, 0);
    __syncthreads();
    int cur = 0;
#pragma unroll 1
    for (int kt = 0; kt < nkt; ++kt) {
        if (kt + 1 < nkt) STAGE((kt + 1) << 6, cur ^ 1);
        const char* sAc = sA + cur * ASZ;
        const char* sBc = sB + cur * 16384;
#pragma unroll
        for (int ks = 0; ks < 2; ++ks) {
            bf16x8 af[2];
#pragma unroll
            for (int mi = 0; mi < 2; ++mi) {
                int row = wm * 32 + mi * 16 + l16;
                if constexpr (A_F32) {
                    int c0 = (ks * 8 + g * 2) ^ (row & 15);
                    int c1 = (ks * 8 + g * 2 + 1) ^ (row & 15);
                    f32x4 lo = *(const f32x4*)(sAc + row * 256 + c0 * 16);
                    f32x4 hi = *(const f32x4*)(sAc + row * 256 + c1 * 16);
                    union { unsigned u[4]; bf16x8 v; } cv;
                    cv.u[0] = cvt_pk_bf16(lo[0], lo[1]);
                    cv.u[1] = cvt_pk_bf16(lo[2], lo[3]);
                    cv.u[2] = cvt_pk_bf16(hi[0], hi[1]);
                    cv.u[3] = cvt_pk_bf16(hi[2], hi[3]);
                    af[mi] = cv.v;
                } else {
                    int c = (ks * 4 + g) ^ (row & 7);
                    af[mi] = *(const bf16x8*)(sAc + row * 128 + c * 16);
                }
            }
#pragma unroll
            for (int ni = 0; ni < 4; ++ni) {
                int row = wn * 64 + ni * 16 + l16;
                int c = (ks * 4 + g) ^ (row & 7);
                bf16x8 bfr = *(const bf16x8*)(sBc + row * 128 + c * 16);
#pragma unroll
                for (int mi = 0; mi < 2; ++mi)
                    acc[mi][ni] = mfma16(af[mi], bfr, acc[mi][ni]);
            }
        }
        __syncthreads();
        cur ^= 1;
    }
    // epilogue: bias + scale + store. C/D layout: col = lane&15, row = g*4 + r
#pragma unroll
    for (int ni = 0; ni < 4; ++ni) {
        int col = n0 + wn * 64 + ni * 16 + l16;
        float bn = bias[col];
#pragma unroll
        for (int mi = 0; mi < 2; ++mi) {
            int rbase = m0 + wm * 32 + mi * 16 + g * 4;
#pragma unroll
            for (int r = 0; r < 4; ++r) {
                float v = (acc[mi][ni][r] + bn) * cscale;
                if constexpr (OUT_F32)
                    ((float*)Cp)[(size_t)(rbase + r) * N + col] = v;
                else
                    ((unsigned short*)Cp)[(size_t)(rbase + r) * N + col] = f2bf(v);
            }
        }
    }
}

// ---------------------------------------------------------------------------
// Per-head V transpose: V2[(b*2048+s)][1024] bf16 -> Vt[(bh*64+d)][2048] bf16
// ---------------------------------------------------------------------------
__global__ __launch_bounds__(256) void k_vtrans(const unsigned short* __restrict__ V2,
                                                unsigned short* __restrict__ Vt) {
    __shared__ unsigned short tile[64][72];   // [d][s]
    const int tid = threadIdx.x;
    const int s0 = blockIdx.x * 64;
    const int bh = blockIdx.y, b = bh >> 4, h = bh & 15;
#pragma unroll
    for (int j = 0; j < 2; ++j) {
        int c = j * 256 + tid;
        int sr = c >> 3, dc = c & 7;
        union { u32x4 v; unsigned short s[8]; } t;
        t.v = *(const u32x4*)(V2 + (size_t)(b * 2048 + s0 + sr) * 1024 + h * 64 + dc * 8);
#pragma unroll
        for (int e = 0; e < 8; ++e) tile[dc * 8 + e][sr] = t.s[e];
    }
    __syncthreads();
#pragma unroll
    for (int j = 0; j < 2; ++j) {
        int c = j * 256 + tid;
        int dr = c >> 3, sc = c & 7;
        union { unsigned short s[8]; u32x4 v; } t;
#pragma unroll
        for (int e = 0; e < 8; ++e) t.s[e] = tile[dr][sc * 8 + e];
        *(u32x4*)(Vt + ((size_t)bh * 64 + dr) * 2048 + s0 + sc * 8) = t.v;
    }
}

// ---------------------------------------------------------------------------
// Causal flash attention, 256-thread blocks for 2 blocks/CU.
// Grid 512 flat, XCD-swizzled. Block handles q-tiles {x, 31-x} of 64 rows
// (4 waves x 16 q-rows) -> 33 kv-tiles of 64 per block (uniform).
// K/V staged in XOR-swizzled LDS (global_load_lds, linear dest +
// pre-swizzled source), double-buffered, stage-before-compute.
// Swapped QK^T (lane owns q = lane&15 -> softmax lane-local), exp2 domain
// (0.125*log2e folded into Q projection), defer-max, setprio around MFMA.
// P -> per-wave swizzled LDS -> PV as O^T = V^T * P^T. ctx written bf16.
// ---------------------------------------------------------------------------
__global__ __launch_bounds__(256) void k_attn(const unsigned short* __restrict__ Q2,
                                              const unsigned short* __restrict__ K2,
                                              const unsigned short* __restrict__ Vt,
                                              unsigned short* __restrict__ ctx) {
    __shared__ __align__(16) char sK[2][8192];   // 64 kv x 64 d bf16, chunk-swizzled
    __shared__ __align__(16) char sV[2][8192];   // 64 d x 64 kv bf16, chunk-swizzled
    __shared__ __align__(16) char sP[4][2048];   // per-wave P^T: 16 q x 64 kv bf16

    const int tid = threadIdx.x, w = tid >> 6, lane = tid & 63;
    const int g = lane >> 4, l16 = lane & 15;
    // bijective XCD swizzle: 512 blocks, 64 consecutive logical ids per XCD
    const int bid = blockIdx.x;
    const int lid = (bid & 7) * 64 + (bid >> 3);
    const int xq = lid & 15, bh = lid >> 4;
    const int b = bh >> 4, h = bh & 15;
    const int swzl = (l16 & 7) << 4;

    // staging source addresses (rule 21: pre-swizzled source, linear LDS dest)
    const int r0 = tid >> 3;                      // 0..31
    const int sc0 = (tid & 7) ^ (r0 & 7);         // same for r0+32
    const unsigned short* ksrc0 = K2 + (size_t)(b * 2048 + r0) * 1024 + h * 64 + sc0 * 8;
    const unsigned short* ksrc1 = ksrc0 + 32 * 1024;
    const unsigned short* vsrc0 = Vt + ((size_t)bh * 64 + r0) * 2048 + sc0 * 8;
    const unsigned short* vsrc1 = vsrc0 + 32 * 2048;
    char* const myp = sP[w];

#pragma unroll 1
    for (int t2 = 0; t2 < 2; ++t2) {
        const int t = t2 ? (31 - xq) : xq;        // q-tile index (64 rows)
        const int wq0 = t * 64 + w * 16;          // first q row of this wave
        const int qg = wq0 + l16;                 // q owned by this lane

        const unsigned short* qp = Q2 + (size_t)(b * 2048 + wq0 + l16) * 1024 + h * 64;
        bf16x8 qf0 = *(const bf16x8*)(qp + g * 8);
        bf16x8 qf1 = *(const bf16x8*)(qp + 32 + g * 8);

        f32x4 accO[4];
#pragma unroll
        for (int i = 0; i < 4; ++i) accO[i] = (f32x4){0.f, 0.f, 0.f, 0.f};
        float m = -1e30f, lsum = 0.f;

        const int nkv = t + 1;
        __syncthreads();                          // prev tile's reads done
        gload16(ksrc0, sK[0] + tid * 16);
        gload16(ksrc1, sK[0] + 4096 + tid * 16);
        gload16(vsrc0, sV[0] + tid * 16);
        gload16(vsrc1, sV[0] + 4096 + tid * 16);

#pragma unroll 1
        for (int kt = 0; kt < nkv; ++kt) {
            const int cur = kt & 1;
            const int kv0 = kt * 64;
            __syncthreads();                      // drains vmcnt: buf[cur] ready
            if (kt + 1 < nkv) {
                gload16(ksrc0 + (size_t)(kv0 + 64) * 1024, sK[cur ^ 1] + tid * 16);
                gload16(ksrc1 + (size_t)(kv0 + 64) * 1024, sK[cur ^ 1] + 4096 + tid * 16);
                gload16(vsrc0 + (kv0 + 64), sV[cur ^ 1] + tid * 16);
                gload16(vsrc1 + (kv0 + 64), sV[cur ^ 1] + 4096 + tid * 16);
            }
            const char* kb = sK[cur];
            const char* vb = sV[cur];
            const bool needmask = (kt == t);      // only diagonal tile masks
            float s[16];
            __builtin_amdgcn_s_setprio(1);
#pragma unroll
            for (int blk = 0; blk < 4; ++blk) {
                const int rl = blk * 16 + l16;
                const char* krow = kb + rl * 128;
                bf16x8 kf0 = *(const bf16x8*)(krow + ((g << 4) ^ swzl));
                bf16x8 kf1 = *(const bf16x8*)(krow + (((4 + g) << 4) ^ swzl));
                f32x4 a = (f32x4){0.f, 0.f, 0.f, 0.f};
                a = mfma16(kf0, qf0, a);
                a = mfma16(kf1, qf1, a);
#pragma unroll
                for (int r = 0; r < 4; ++r) s[blk * 4 + r] = a[r];
            }
            __builtin_amdgcn_s_setprio(0);
            if (needmask) {
#pragma unroll
                for (int j = 0; j < 16; ++j) {
                    int kvg = kv0 + (j >> 2) * 16 + g * 4 + (j & 3);
                    if (kvg > qg) s[j] = -1e9f;
                }
            }
            float mx = fmaxf(fmaxf(fmaxf(s[0], s[1]), fmaxf(s[2], s[3])),
                             fmaxf(fmaxf(s[4], s[5]), fmaxf(s[6], s[7])));
            mx = fmaxf(mx, fmaxf(fmaxf(fmaxf(s[8], s[9]), fmaxf(s[10], s[11])),
                                 fmaxf(fmaxf(s[12], s[13]), fmaxf(s[14], s[15]))));
            mx = fmaxf(mx, __shfl_xor(mx, 16));
            mx = fmaxf(mx, __shfl_xor(mx, 32));
            // defer-max (T13): skip rescale while tile max stays within 8 (log2)
            if (__any(mx > m + 8.f)) {
                float mnew = fmaxf(m, mx);
                float scale = __builtin_exp2f(m - mnew);
                lsum *= scale;
#pragma unroll
                for (int dt = 0; dt < 4; ++dt) accO[dt] = accO[dt] * scale;
                m = mnew;
            }
            float ps = 0.f;
            unsigned pk[8];
#pragma unroll
            for (int j = 0; j < 8; ++j) {
                float p0 = __builtin_exp2f(s[2 * j] - m);
                float p1 = __builtin_exp2f(s[2 * j + 1] - m);
                ps += p0 + p1;
                pk[j] = cvt_pk_bf16(p0, p1);
            }
            ps += __shfl_xor(ps, 16);
            ps += __shfl_xor(ps, 32);
            lsum += ps;
            // write P^T (bf16) to per-wave swizzled LDS
#pragma unroll
            for (int blk = 0; blk < 4; ++blk) {
                u32x2 pw = {pk[blk * 2], pk[blk * 2 + 1]};
                *(u32x2*)(myp + l16 * 128 + ((blk * 32 + g * 8) ^ swzl)) = pw;
            }
            // PV: O^T[d][q] += V^T * P^T
            __builtin_amdgcn_s_setprio(1);
#pragma unroll
            for (int kvh = 0; kvh < 2; ++kvh) {
                bf16x8 pf = *(const bf16x8*)(myp + l16 * 128 + ((kvh * 64 + g * 16) ^ swzl));
#pragma unroll
                for (int dt = 0; dt < 4; ++dt) {
                    const int rv = dt * 16 + l16;
                    bf16x8 vf = *(const bf16x8*)(vb + rv * 128 + (((kvh * 4 + g) << 4) ^ swzl));
                    accO[dt] = mfma16(vf, pf, accO[dt]);
                }
            }
            __builtin_amdgcn_s_setprio(0);
        }
        float inv = 1.f / lsum;
        // O^T: lane owns col q=l16; row d = dt*16 + g*4 + r -> ctx bf16 [4096][1024]
        unsigned short* cp = ctx + (size_t)(b * 2048 + wq0 + l16) * 1024 + h * 64 + g * 4;
#pragma unroll
        for (int dt = 0; dt < 4; ++dt) {
            u32x2 o;
            o[0] = cvt_pk_bf16(accO[dt][0] * inv, accO[dt][1] * inv);
            o[1] = cvt_pk_bf16(accO[dt][2] * inv, accO[dt][3] * inv);
            *(u32x2*)(cp + dt * 16) = o;
        }
    }
}

// ---------------------------------------------------------------------------
extern "C" void kernel_launch(void* const* d_in, const int* in_sizes, int n_in,
                              void* d_out, int out_size, void* d_ws, size_t ws_size,
                              hipStream_t stream) {
    const float* query = (const float*)d_in[0];
    const float* key   = (const float*)d_in[1];
    const float* value = (const float*)d_in[2];
    // d_in[3] = mask: fixed causal tril, applied analytically
    const float* wq = (const float*)d_in[4];
    const float* bq = (const float*)d_in[5];
    const float* wk = (const float*)d_in[6];
    const float* bk = (const float*)d_in[7];
    const float* wv = (const float*)d_in[8];
    const float* bv = (const float*)d_in[9];
    const float* wo = (const float*)d_in[10];
    const float* bo = (const float*)d_in[11];
    float* out = (float*)d_out;

    char* ws = (char*)d_ws;
    unsigned short* Wtq = (unsigned short*)ws;                 // 4 x 2MB
    unsigned short* Wtk = Wtq + 1024 * 1024;
    unsigned short* Wtv = Wtk + 1024 * 1024;
    unsigned short* Wto = Wtv + 1024 * 1024;
    unsigned short* Q2  = Wto + 1024 * 1024;                   // 3 x 8MB bf16 [4096][1024]
    unsigned short* K2  = Q2 + 4096 * 1024;
    unsigned short* V2  = K2 + 4096 * 1024;
    unsigned short* Vt  = V2 + 4096 * 1024;                    // 8MB bf16 [32*64][2048]
    unsigned short* ctx = Vt + 4096 * 1024;                    // 8MB bf16 [4096][1024]

    dim3 blk(256);
    k_wtrans<<<dim3(16, 16), blk, 0, stream>>>(wq, Wtq);
    k_wtrans<<<dim3(16, 16), blk, 0, stream>>>(wk, Wtk);
    k_wtrans<<<dim3(16, 16), blk, 0, stream>>>(wv, Wtv);
    k_wtrans<<<dim3(16, 16), blk, 0, stream>>>(wv, Wtv);
    k_wtrans<<<dim3(16, 16), blk, 0, stream>>>(wo, Wto);

    // exp2-domain scale 0.125*log2(e) folded into Q projection
    k_gemm<1, 0><<<dim3(64, 8), blk, 65536, stream>>>(query, Wtq, bq, Q2, 4096, 1024, 1024, 0.18033688011112042f);
    k_gemm<1, 0><<<dim3(64, 8), blk, 65536, stream>>>(key,   Wtk, bk, K2, 4096, 1024, 1024, 1.0f);
    k_gemm<1, 0><<<dim3(64, 8), blk, 65536, stream>>>(value, Wtv, bv, V2, 4096, 1024, 1024, 1.0f);

    k_vtrans<<<dim3(32, 32), blk, 0, stream>>>(V2, Vt);
    k_attn<<<dim3(512), blk, 0, stream>>>(Q2, K2, Vt, ctx);

    k_gemm<0, 1><<<dim3(64, 8), blk, 49152, stream>>>(ctx, Wto, bo, out, 4096, 1024, 1024, 1.0f);
}